// Round 11
// baseline (111.214 us; speedup 1.0000x reference)
//
#include <hip/hip_runtime.h>
#include <math.h>
#include <limits.h>

#define WAVE 64
#define KMAX 32   // K is 32 in this problem
#define IMAX 96   // max inverse-degree; Poisson(32) tail at 96 is < 1e-20

// tanh(z) = 1 - 2/(exp(2z)+1); __expf -> v_exp_f32, ~1e-7 abs err.
__device__ __forceinline__ float nvval(float d, float s) {
    float z = 0.7f * d + 0.3f * s + 0.5f;
    float e = __expf(z);
    return 1.0f - 2.0f / (e + 1.0f);
}
__device__ __forceinline__ float clamp01(float x) {
    return fminf(fmaxf(x, 0.0f), 1.0f);
}

// K1: Mbits (register-built, plain coalesced stores) + zero invcnt
// (folds the old memset dispatch into this kernel; K1 completes before K2).
__global__ void mbits_kernel(const int* __restrict__ nbr, int N, int K, int W,
                             unsigned* __restrict__ Mbits, int* __restrict__ invcnt) {
    int tid = blockIdx.x * blockDim.x + threadIdx.x;
    if (tid < N) invcnt[tid] = 0;
    int i = tid / WAVE;
    int lane = tid & (WAVE - 1);
    if (i >= N) return;
    int val = (lane < K) ? nbr[(size_t)i * K + lane] : INT_MAX;
    unsigned mybits = 0;  // word 'lane' of Mbits row i
    #pragma unroll
    for (int t = 0; t < KMAX; ++t) {
        int vt = __shfl(val, t);
        if ((vt >> 5) == lane) mybits |= 1u << (vt & 31);
    }
    if (lane < W) Mbits[(size_t)i * W + lane] = mybits;
}

// K2: build from the Mbits row (dedup+sort free: the bitset IS the sorted
// set) fused with phase1's chain. Dual-m membership loop: low lanes probe
// m=2t, high lanes m=2t+1 -- 16 rounds, and its ballots directly yield
// cnt_m, H, and per-lane hmTerm. (Unchanged from R10-passing version.)
__global__ void __launch_bounds__(256) build_phase1(
        const float* __restrict__ dyn, const float* __restrict__ stat,
        const unsigned* __restrict__ Mbits,
        int N, int K, int W,
        int* __restrict__ nbrs_sorted, int* __restrict__ invcnt,
        int* __restrict__ invlist, float* __restrict__ Vcomp,
        float* __restrict__ Dval) {
    __shared__ float s_nv[4 * KMAX * KMAX];   // [wave][m][lane], 16 KB
    __shared__ int s_sortedAll[4 * KMAX];
    int tid = blockIdx.x * blockDim.x + threadIdx.x;
    int j = tid / WAVE;
    int lane = threadIdx.x & (WAVE - 1);
    int l = lane & 31;
    int half = lane >> 5;
    int waveid = threadIdx.x >> 6;
    if (j >= N) return;
    float* s_row = &s_nv[waveid * KMAX * KMAX];
    int* s_sorted = &s_sortedAll[waveid * KMAX];

    // ---- build: read own Mbits row; prefix-scan popcounts; scatter ids ----
    unsigned word = Mbits[(size_t)j * W + lane];
    int myc = __popc(word);
    int inc = myc;
    #pragma unroll
    for (int off = 1; off < 64; off <<= 1) {
        int y = __shfl_up(inc, off);
        if (lane >= off) inc += y;
    }
    int base = inc - myc;       // exclusive prefix = sorted rank base
    int deg = __shfl(inc, 63);  // total distinct neighbors (<= 32)
    {
        unsigned wb = word;
        int r = base;
        while (wb) {
            int b = __ffs(wb) - 1;
            s_sorted[r] = (lane << 5) | b;   // neighbor id, ascending
            wb &= wb - 1;
            ++r;
        }
    }
    bool valid32 = (lane < deg);            // deg<=32: only low lanes
    int c = valid32 ? s_sorted[lane] : INT_MAX;
    if (lane < K) nbrs_sorted[(size_t)j * K + lane] = c;

    // invlist append: direct (sorted lane already owns its c)
    int psort = -1;
    if (valid32) {
        psort = atomicAdd(&invcnt[c], 1);
        if (psort >= 0 && psort < IMAX) invlist[(size_t)c * IMAX + psort] = j;
    }
    float statj = stat[j];
    float sk = valid32 ? stat[c] : 0.0f;
    int c_m = __shfl(c, l);       // mirror c to high half
    float sk_m = __shfl(sk, l);   // mirror stat[c] to high half
    bool validl = (l < deg);

    // Dval: direct tanh values of ROW j (for phase2's setup)
    if (lane < K)
        Dval[(size_t)j * K + lane] = valid32 ? nvval(dyn[(size_t)j * N + c], sk) : 0.0f;

    // dir bits (lanes 0..31): j in nbr(c_m)?
    unsigned dirbit = 0;
    if (valid32) {
        unsigned w = Mbits[(size_t)c * W + (j >> 5)];
        dirbit = (w >> (j & 31)) & 1u;
    }
    unsigned dirmask = (unsigned)__ballot(dirbit != 0);
    float dv = 0.0f;
    if (dirbit) dv = nvval(dyn[(size_t)c * N + j], statj);  // lane m holds dval_m

    // ---- dual-m membership loop: 16 rounds cover m = 0..31 ----
    unsigned hmTerm = 0;
    unsigned H = 0;
    int mycnt = 0;
    #pragma unroll
    for (int t = 0; t < KMAX / 2; ++t) {
        int mh = 2 * t + half;
        int cm = __shfl(c, mh);   // bpermute; INT_MAX if mh >= deg
        unsigned b = 0;
        if (cm < N && validl) {
            unsigned w = Mbits[(size_t)cm * W + (c_m >> 5)];
            b = (w >> (c_m & 31)) & 1u;
        }
        bool termb = (b != 0) && (l < mh) && (c_m < j);
        unsigned long long ball = __ballot(b != 0);
        unsigned long long ballT = __ballot(termb);
        unsigned low = (unsigned)ball;
        unsigned high = (unsigned)(ball >> 32);
        unsigned lowT = (unsigned)ballT;
        unsigned highT = (unsigned)(ballT >> 32);
        if (lane == 2 * t) mycnt = __popc(low);          // cnt_m on lane m
        if (lane == 2 * t + 1) mycnt = __popc(high);
        hmTerm |= ((lowT >> l) & 1u) << (2 * t);
        hmTerm |= ((highT >> l) & 1u) << (2 * t + 1);
        H |= (lowT ? 1u : 0u) << (2 * t);                // uniform
        H |= (highT ? 1u : 0u) << (2 * t + 1);
        if (termb)
            s_row[mh * KMAX + l] = nvval(dyn[(size_t)cm * N + c_m], sk_m);
    }
    if (lane >= 32) hmTerm = 0;  // high half must not feed the reduce

    // ---- the sequential chain: only v crosses iterations ----
    float v = 0.0f;
    #pragma unroll
    for (int m = 0; m < KMAX; ++m) {
        float num = 0.0f;
        if (H & (1u << m)) {
            float tt = 0.0f;
            if ((hmTerm >> m) & 1u) tt = s_row[m * KMAX + lane] * v;
            num = tt;
            num += __shfl_xor(num, 16);  // data lives in lanes 0..31 only
            num += __shfl_xor(num, 8);
            num += __shfl_xor(num, 4);
            num += __shfl_xor(num, 2);
            num += __shfl_xor(num, 1);
        }
        float val2;
        if ((dirmask >> m) & 1u) val2 = dv;
        else if (mycnt > 0) val2 = 0.8f * num / (float)mycnt;
        else val2 = 0.5f * statj;
        val2 = clamp01(val2);
        if (lane == m) v = val2;
    }
    if (valid32 && psort >= 0 && psort < IMAX)
        Vcomp[(size_t)c * IMAX + psort] = v;  // compact, invlist order
}

// K3 (phase2): vectorized clear (ds_write_b128), vectorized sweep
// (ds_read_b128 + float4 coalesced out stores), rcp instead of div.
// Accumulator structure unchanged (separate int cnt + float num LDS
// atomics; u64 packed atomic is BANNED -- it crashed R7/R8).
__global__ void __launch_bounds__(256) phase2(
        const float* __restrict__ stat,
        const int* __restrict__ nbrs_sorted,
        const int* __restrict__ invcnt, const int* __restrict__ invlist,
        const float* __restrict__ Vcomp, const float* __restrict__ Dval,
        int N, int K, float* __restrict__ out) {
    extern __shared__ char smem[];
    int* s_cnt = (int*)smem;                    // N ints (16B aligned)
    float* s_num = (float*)(s_cnt + N);         // N floats (16B aligned, N%4==0)
    int* s_nbr = (int*)(s_num + N);             // KMAX
    float* s_nv = (float*)(s_nbr + KMAX);       // KMAX
    int* s_icnt = (int*)(s_nv + KMAX);          // KMAX
    __shared__ int s_me;

    int i = blockIdx.x;
    int tid = threadIdx.x;

    {   // vectorized LDS clear: b128 stores
        int4* c4 = (int4*)s_cnt;
        float4* n4 = (float4*)s_num;
        int nv4 = N >> 2;
        int4 zi = {0, 0, 0, 0};
        float4 zf = {0.0f, 0.0f, 0.0f, 0.0f};
        for (int t = tid; t < nv4; t += blockDim.x) { c4[t] = zi; n4[t] = zf; }
    }
    if (tid < K) {
        int c = nbrs_sorted[(size_t)i * K + tid];
        s_nbr[tid] = c;
        s_nv[tid] = Dval[(size_t)i * K + tid];
        int m = (c < N) ? invcnt[c] : 0;
        s_icnt[tid] = (m < 0) ? 0 : ((m < IMAX) ? m : IMAX);  // defensive clamp
    }
    if (tid == 0) {
        int m = invcnt[i];
        s_me = (m < 0) ? 0 : ((m < IMAX) ? m : IMAX);
    }
    __syncthreads();

    {   // scatter: 32 k-slots x 8 threads; vectorized invlist/Vcomp loads
        int k = tid >> 3;
        int sub = tid & 7;
        if (k < K) {
            int c = s_nbr[k];
            int m = s_icnt[k];
            float nv = s_nv[k];
            if (c < N) {
                const int4* il4 = (const int4*)&invlist[(size_t)c * IMAX];
                const float4* vc4 = (const float4*)&Vcomp[(size_t)c * IMAX];
                for (int base = sub * 4; base < m; base += 32) {
                    int4 js = il4[base >> 2];
                    float4 vs = vc4[base >> 2];
                    int jj[4] = {js.x, js.y, js.z, js.w};
                    float vv[4] = {vs.x, vs.y, vs.z, vs.w};
                    #pragma unroll
                    for (int t = 0; t < 4; ++t) {
                        int e = base + t;
                        if (e < m) {
                            int j = jj[t] & (N - 1);  // defensive: stay in LDS
                            atomicAdd(&s_cnt[j], 1);
                            if (c < i && c < j)
                                atomicAdd(&s_num[j], nv * vv[t]);
                        }
                    }
                }
            }
        }
    }
    __syncthreads();

    // dir-fill: j in nbr(i) -> value s_nv[k]; marker cnt=-1
    if (tid < K) {
        int c = s_nbr[tid];
        if (c < N) { s_cnt[c] = -1; s_num[c] = s_nv[tid]; }
    }
    __syncthreads();

    // skip-fill: i in nbr(j) -> phase1's final value overrides everything
    int me = s_me;
    for (int e = tid; e < me; e += blockDim.x) {
        int j = invlist[(size_t)i * IMAX + e] & (N - 1);  // defensive
        s_cnt[j] = -1;
        s_num[j] = Vcomp[(size_t)i * IMAX + e];
    }
    __syncthreads();

    // sweep: 4 consecutive j per thread; b128 LDS reads + float4 out stores
    for (int base = tid * 4; base < (N & ~3); base += (int)blockDim.x * 4) {
        int4 cv = *(const int4*)&s_cnt[base];
        float4 nm = *(const float4*)&s_num[base];
        int cp[4] = {cv.x, cv.y, cv.z, cv.w};
        float np[4] = {nm.x, nm.y, nm.z, nm.w};
        float op[4];
        #pragma unroll
        for (int t = 0; t < 4; ++t) {
            int j = base + t;
            int cnt = cp[t];
            float val;
            if (j == i) val = 1.0f;
            else if (cnt < 0) val = np[t];
            else if (cnt > 0)
                val = 0.8f * np[t] * __builtin_amdgcn_rcpf((float)cnt);
            else val = 0.5f * stat[j];
            op[t] = clamp01(val);
        }
        float4 o = {op[0], op[1], op[2], op[3]};
        *(float4*)&out[(size_t)i * N + base] = o;
    }
    for (int j = (N & ~3) + tid; j < N; j += blockDim.x) {  // tail (N%4 != 0)
        int cnt = s_cnt[j];
        float val;
        if (j == i) val = 1.0f;
        else if (cnt < 0) val = s_num[j];
        else if (cnt > 0) val = 0.8f * s_num[j] / (float)cnt;
        else val = 0.5f * stat[j];
        out[(size_t)i * N + j] = clamp01(val);
    }
}

extern "C" void kernel_launch(void* const* d_in, const int* in_sizes, int n_in,
                              void* d_out, int out_size, void* d_ws, size_t ws_size,
                              hipStream_t stream) {
    const float* dyn = (const float*)d_in[0];
    const float* stat = (const float*)d_in[1];
    const int* nbr = (const int*)d_in[2];
    int N = in_sizes[1];
    int K = in_sizes[2] / N;
    int W = (N + 31) / 32;
    float* out = (float*)d_out;

    char* ws = (char*)d_ws;
    size_t offIC = 0;                                        // invcnt (zeroed in K1)
    size_t offM = offIC + (size_t)N * sizeof(int);           // Mbits
    size_t offIL = offM + (size_t)N * W * sizeof(unsigned);  // invlist
    size_t offVC = offIL + (size_t)N * IMAX * sizeof(int);   // Vcomp
    size_t offNbr = offVC + (size_t)N * IMAX * sizeof(float);// nbrs_sorted
    size_t offDv = offNbr + (size_t)N * K * sizeof(int);     // Dval
    int* invcnt = (int*)(ws + offIC);
    unsigned* Mbits = (unsigned*)(ws + offM);
    int* invlist = (int*)(ws + offIL);
    float* Vcomp = (float*)(ws + offVC);
    int* nbrs_sorted = (int*)(ws + offNbr);
    float* Dval = (float*)(ws + offDv);

    int threads = 256;
    int blocksWave = (N * WAVE + threads - 1) / threads;  // one wave per row/col
    mbits_kernel<<<blocksWave, threads, 0, stream>>>(nbr, N, K, W, Mbits, invcnt);
    build_phase1<<<blocksWave, threads, 0, stream>>>(dyn, stat, Mbits, N, K, W,
                                                     nbrs_sorted, invcnt, invlist,
                                                     Vcomp, Dval);
    size_t smem = (size_t)N * 8 + (size_t)KMAX * 12 + 16;
    phase2<<<N, threads, smem, stream>>>(stat, nbrs_sorted, invcnt, invlist,
                                         Vcomp, Dval, N, K, out);
}

// Round 12
// 108.568 us; speedup vs baseline: 1.0244x; 1.0244x over previous
//
#include <hip/hip_runtime.h>
#include <math.h>
#include <limits.h>

#define WAVE 64
#define KMAX 32   // K is 32 in this problem
#define IMAX 96   // max inverse-degree; Poisson(32) tail at 96 is < 1e-20

// tanh(z) = 1 - 2/(exp(2z)+1); __expf -> v_exp_f32, ~1e-7 abs err.
__device__ __forceinline__ float nvval(float d, float s) {
    float z = 0.7f * d + 0.3f * s + 0.5f;
    float e = __expf(z);
    return 1.0f - 2.0f / (e + 1.0f);
}
__device__ __forceinline__ float clamp01(float x) {
    return fminf(fmaxf(x, 0.0f), 1.0f);
}

// K1: Mbits (register-built, plain coalesced stores) + zero invcnt
// (folds the old memset dispatch into this kernel; K1 completes before K2).
__global__ void mbits_kernel(const int* __restrict__ nbr, int N, int K, int W,
                             unsigned* __restrict__ Mbits, int* __restrict__ invcnt) {
    int tid = blockIdx.x * blockDim.x + threadIdx.x;
    if (tid < N) invcnt[tid] = 0;
    int i = tid / WAVE;
    int lane = tid & (WAVE - 1);
    if (i >= N) return;
    int val = (lane < K) ? nbr[(size_t)i * K + lane] : INT_MAX;
    unsigned mybits = 0;  // word 'lane' of Mbits row i
    #pragma unroll
    for (int t = 0; t < KMAX; ++t) {
        int vt = __shfl(val, t);
        if ((vt >> 5) == lane) mybits |= 1u << (vt & 31);
    }
    if (lane < W) Mbits[(size_t)i * W + lane] = mybits;
}

// K2: build from the Mbits row (dedup+sort free: the bitset IS the sorted
// set) fused with phase1's chain. Dual-m membership loop: low lanes probe
// m=2t, high lanes m=2t+1 -- 16 rounds, and its ballots directly yield
// cnt_m, H, and per-lane hmTerm. (Unchanged from R10-passing version.)
__global__ void __launch_bounds__(256) build_phase1(
        const float* __restrict__ dyn, const float* __restrict__ stat,
        const unsigned* __restrict__ Mbits,
        int N, int K, int W,
        int* __restrict__ nbrs_sorted, int* __restrict__ invcnt,
        int* __restrict__ invlist, float* __restrict__ Vcomp,
        float* __restrict__ Dval) {
    __shared__ float s_nv[4 * KMAX * KMAX];   // [wave][m][lane], 16 KB
    __shared__ int s_sortedAll[4 * KMAX];
    int tid = blockIdx.x * blockDim.x + threadIdx.x;
    int j = tid / WAVE;
    int lane = threadIdx.x & (WAVE - 1);
    int l = lane & 31;
    int half = lane >> 5;
    int waveid = threadIdx.x >> 6;
    if (j >= N) return;
    float* s_row = &s_nv[waveid * KMAX * KMAX];
    int* s_sorted = &s_sortedAll[waveid * KMAX];

    // ---- build: read own Mbits row; prefix-scan popcounts; scatter ids ----
    unsigned word = Mbits[(size_t)j * W + lane];
    int myc = __popc(word);
    int inc = myc;
    #pragma unroll
    for (int off = 1; off < 64; off <<= 1) {
        int y = __shfl_up(inc, off);
        if (lane >= off) inc += y;
    }
    int base = inc - myc;       // exclusive prefix = sorted rank base
    int deg = __shfl(inc, 63);  // total distinct neighbors (<= 32)
    {
        unsigned wb = word;
        int r = base;
        while (wb) {
            int b = __ffs(wb) - 1;
            s_sorted[r] = (lane << 5) | b;   // neighbor id, ascending
            wb &= wb - 1;
            ++r;
        }
    }
    bool valid32 = (lane < deg);            // deg<=32: only low lanes
    int c = valid32 ? s_sorted[lane] : INT_MAX;
    if (lane < K) nbrs_sorted[(size_t)j * K + lane] = c;

    // invlist append: direct (sorted lane already owns its c)
    int psort = -1;
    if (valid32) {
        psort = atomicAdd(&invcnt[c], 1);
        if (psort >= 0 && psort < IMAX) invlist[(size_t)c * IMAX + psort] = j;
    }
    float statj = stat[j];
    float sk = valid32 ? stat[c] : 0.0f;
    int c_m = __shfl(c, l);       // mirror c to high half
    float sk_m = __shfl(sk, l);   // mirror stat[c] to high half
    bool validl = (l < deg);

    // Dval: direct tanh values of ROW j (for phase2's setup)
    if (lane < K)
        Dval[(size_t)j * K + lane] = valid32 ? nvval(dyn[(size_t)j * N + c], sk) : 0.0f;

    // dir bits (lanes 0..31): j in nbr(c_m)?
    unsigned dirbit = 0;
    if (valid32) {
        unsigned w = Mbits[(size_t)c * W + (j >> 5)];
        dirbit = (w >> (j & 31)) & 1u;
    }
    unsigned dirmask = (unsigned)__ballot(dirbit != 0);
    float dv = 0.0f;
    if (dirbit) dv = nvval(dyn[(size_t)c * N + j], statj);  // lane m holds dval_m

    // ---- dual-m membership loop: 16 rounds cover m = 0..31 ----
    unsigned hmTerm = 0;
    unsigned H = 0;
    int mycnt = 0;
    #pragma unroll
    for (int t = 0; t < KMAX / 2; ++t) {
        int mh = 2 * t + half;
        int cm = __shfl(c, mh);   // bpermute; INT_MAX if mh >= deg
        unsigned b = 0;
        if (cm < N && validl) {
            unsigned w = Mbits[(size_t)cm * W + (c_m >> 5)];
            b = (w >> (c_m & 31)) & 1u;
        }
        bool termb = (b != 0) && (l < mh) && (c_m < j);
        unsigned long long ball = __ballot(b != 0);
        unsigned long long ballT = __ballot(termb);
        unsigned low = (unsigned)ball;
        unsigned high = (unsigned)(ball >> 32);
        unsigned lowT = (unsigned)ballT;
        unsigned highT = (unsigned)(ballT >> 32);
        if (lane == 2 * t) mycnt = __popc(low);          // cnt_m on lane m
        if (lane == 2 * t + 1) mycnt = __popc(high);
        hmTerm |= ((lowT >> l) & 1u) << (2 * t);
        hmTerm |= ((highT >> l) & 1u) << (2 * t + 1);
        H |= (lowT ? 1u : 0u) << (2 * t);                // uniform
        H |= (highT ? 1u : 0u) << (2 * t + 1);
        if (termb)
            s_row[mh * KMAX + l] = nvval(dyn[(size_t)cm * N + c_m], sk_m);
    }
    if (lane >= 32) hmTerm = 0;  // high half must not feed the reduce

    // ---- the sequential chain: only v crosses iterations ----
    float v = 0.0f;
    #pragma unroll
    for (int m = 0; m < KMAX; ++m) {
        float num = 0.0f;
        if (H & (1u << m)) {
            float tt = 0.0f;
            if ((hmTerm >> m) & 1u) tt = s_row[m * KMAX + lane] * v;
            num = tt;
            num += __shfl_xor(num, 16);  // data lives in lanes 0..31 only
            num += __shfl_xor(num, 8);
            num += __shfl_xor(num, 4);
            num += __shfl_xor(num, 2);
            num += __shfl_xor(num, 1);
        }
        float val2;
        if ((dirmask >> m) & 1u) val2 = dv;
        else if (mycnt > 0) val2 = 0.8f * num / (float)mycnt;
        else val2 = 0.5f * statj;
        val2 = clamp01(val2);
        if (lane == m) v = val2;
    }
    if (valid32 && psort >= 0 && psort < IMAX)
        Vcomp[(size_t)c * IMAX + psort] = v;  // compact, invlist order
}

// K3 (phase2): R10-passing structure. Only surviving R11 change: the
// vectorized (b128) LDS clear. Sweep reverted to scalar (R11's 4-wide
// sweep regressed +3us: bigger live window + 4x fewer outstanding stores
// lost more latency-hiding than the instruction count saved).
__global__ void __launch_bounds__(256) phase2(
        const float* __restrict__ stat,
        const int* __restrict__ nbrs_sorted,
        const int* __restrict__ invcnt, const int* __restrict__ invlist,
        const float* __restrict__ Vcomp, const float* __restrict__ Dval,
        int N, int K, float* __restrict__ out) {
    extern __shared__ char smem[];
    int* s_cnt = (int*)smem;                    // N ints (16B aligned)
    float* s_num = (float*)(s_cnt + N);         // N floats (16B aligned, N%4==0)
    int* s_nbr = (int*)(s_num + N);             // KMAX
    float* s_nv = (float*)(s_nbr + KMAX);       // KMAX
    int* s_icnt = (int*)(s_nv + KMAX);          // KMAX
    __shared__ int s_me;

    int i = blockIdx.x;
    int tid = threadIdx.x;

    {   // vectorized LDS clear: b128 stores (write-only, kept from R11)
        int4* c4 = (int4*)s_cnt;
        float4* n4 = (float4*)s_num;
        int nv4 = N >> 2;
        int4 zi = {0, 0, 0, 0};
        float4 zf = {0.0f, 0.0f, 0.0f, 0.0f};
        for (int t = tid; t < nv4; t += blockDim.x) { c4[t] = zi; n4[t] = zf; }
    }
    if (tid < K) {
        int c = nbrs_sorted[(size_t)i * K + tid];
        s_nbr[tid] = c;
        s_nv[tid] = Dval[(size_t)i * K + tid];
        int m = (c < N) ? invcnt[c] : 0;
        s_icnt[tid] = (m < 0) ? 0 : ((m < IMAX) ? m : IMAX);  // defensive clamp
    }
    if (tid == 0) {
        int m = invcnt[i];
        s_me = (m < 0) ? 0 : ((m < IMAX) ? m : IMAX);
    }
    __syncthreads();

    {   // scatter: 32 k-slots x 8 threads; vectorized invlist/Vcomp loads
        int k = tid >> 3;
        int sub = tid & 7;
        if (k < K) {
            int c = s_nbr[k];
            int m = s_icnt[k];
            float nv = s_nv[k];
            if (c < N) {
                const int4* il4 = (const int4*)&invlist[(size_t)c * IMAX];
                const float4* vc4 = (const float4*)&Vcomp[(size_t)c * IMAX];
                for (int base = sub * 4; base < m; base += 32) {
                    int4 js = il4[base >> 2];
                    float4 vs = vc4[base >> 2];
                    int jj[4] = {js.x, js.y, js.z, js.w};
                    float vv[4] = {vs.x, vs.y, vs.z, vs.w};
                    #pragma unroll
                    for (int t = 0; t < 4; ++t) {
                        int e = base + t;
                        if (e < m) {
                            int j = jj[t] & (N - 1);  // defensive: stay in LDS
                            atomicAdd(&s_cnt[j], 1);
                            if (c < i && c < j)
                                atomicAdd(&s_num[j], nv * vv[t]);
                        }
                    }
                }
            }
        }
    }
    __syncthreads();

    // dir-fill: j in nbr(i) -> value s_nv[k]; marker cnt=-1
    if (tid < K) {
        int c = s_nbr[tid];
        if (c < N) { s_cnt[c] = -1; s_num[c] = s_nv[tid]; }
    }
    __syncthreads();

    // skip-fill: i in nbr(j) -> phase1's final value overrides everything
    int me = s_me;
    for (int e = tid; e < me; e += blockDim.x) {
        int j = invlist[(size_t)i * IMAX + e] & (N - 1);  // defensive
        s_cnt[j] = -1;
        s_num[j] = Vcomp[(size_t)i * IMAX + e];
    }
    __syncthreads();

    // sweep: scalar, coalesced single-pass write of the full row (R10 form)
    for (int j = tid; j < N; j += blockDim.x) {
        int cnt = s_cnt[j];
        float val;
        if (j == i) val = 1.0f;
        else if (cnt < 0) val = s_num[j];
        else if (cnt > 0) val = 0.8f * s_num[j] / (float)cnt;
        else val = 0.5f * stat[j];
        out[(size_t)i * N + j] = clamp01(val);
    }
}

extern "C" void kernel_launch(void* const* d_in, const int* in_sizes, int n_in,
                              void* d_out, int out_size, void* d_ws, size_t ws_size,
                              hipStream_t stream) {
    const float* dyn = (const float*)d_in[0];
    const float* stat = (const float*)d_in[1];
    const int* nbr = (const int*)d_in[2];
    int N = in_sizes[1];
    int K = in_sizes[2] / N;
    int W = (N + 31) / 32;
    float* out = (float*)d_out;

    char* ws = (char*)d_ws;
    size_t offIC = 0;                                        // invcnt (zeroed in K1)
    size_t offM = offIC + (size_t)N * sizeof(int);           // Mbits
    size_t offIL = offM + (size_t)N * W * sizeof(unsigned);  // invlist
    size_t offVC = offIL + (size_t)N * IMAX * sizeof(int);   // Vcomp
    size_t offNbr = offVC + (size_t)N * IMAX * sizeof(float);// nbrs_sorted
    size_t offDv = offNbr + (size_t)N * K * sizeof(int);     // Dval
    int* invcnt = (int*)(ws + offIC);
    unsigned* Mbits = (unsigned*)(ws + offM);
    int* invlist = (int*)(ws + offIL);
    float* Vcomp = (float*)(ws + offVC);
    int* nbrs_sorted = (int*)(ws + offNbr);
    float* Dval = (float*)(ws + offDv);

    int threads = 256;
    int blocksWave = (N * WAVE + threads - 1) / threads;  // one wave per row/col
    mbits_kernel<<<blocksWave, threads, 0, stream>>>(nbr, N, K, W, Mbits, invcnt);
    build_phase1<<<blocksWave, threads, 0, stream>>>(dyn, stat, Mbits, N, K, W,
                                                     nbrs_sorted, invcnt, invlist,
                                                     Vcomp, Dval);
    size_t smem = (size_t)N * 8 + (size_t)KMAX * 12 + 16;
    phase2<<<N, threads, smem, stream>>>(stat, nbrs_sorted, invcnt, invlist,
                                         Vcomp, Dval, N, K, out);
}